// Round 5
// baseline (775.203 us; speedup 1.0000x reference)
//
#include <hip/hip_runtime.h>

// ESIM layer: out = softmax((x@W + b) @ y^T) @ y
// B=64, Sx=Sy=512, D=1024, fp32 in/out.
//
// Round-6: attn rebuilt with T4 counted-vmcnt pipeline:
//  * phase 0: per-wave LDS stripe DOUBLE-buffer via global_load_lds (0 VGPR)
//    + WAIT_VM(16) group-counted (never 0 mid-loop). A-regs depth-2 as before.
//    Issue->use distance ~1 half-step (~620 SIMD cyc) covers L3 (~600).
//    LDS: Y2[2][512][32] (64KB) overlaid by Pbuf[64][520] after phase 0;
//    Red outside overlay. Total 68608B -> still 2 blocks/CU.
//  * phase 2: named-reg B0/B1 depth-2 rotation (regs free after s2 dies),
//    WAIT_VM(8); B prologue issued before the Pbuf barrier.
//  * prep: 3 kernels merged into 1 (fewer launch gaps).
//  * proj unchanged (R4 dbuf version, passed).

typedef float  f32x4  __attribute__((ext_vector_type(4)));
typedef _Float16 f16x8 __attribute__((ext_vector_type(8)));
typedef _Float16 f16x4 __attribute__((ext_vector_type(4)));
typedef __bf16 bf16x8 __attribute__((ext_vector_type(8)));
typedef __bf16 bf16x4 __attribute__((ext_vector_type(4)));

#define MFMA_F16(a, b, c)  __builtin_amdgcn_mfma_f32_16x16x32_f16((a), (b), (c), 0, 0, 0)
#define MFMA_BF16(a, b, c) __builtin_amdgcn_mfma_f32_16x16x32_bf16((a), (b), (c), 0, 0, 0)

#define WAIT_VM(N)  do { asm volatile("s_waitcnt vmcnt(" #N ")" ::: "memory"); \
                         __builtin_amdgcn_sched_barrier(0); } while (0)

__device__ __forceinline__ void async16(const void* g, void* lds) {
    __builtin_amdgcn_global_load_lds(
        (const __attribute__((address_space(1))) unsigned int*)g,
        (__attribute__((address_space(3))) unsigned int*)lds, 16, 0, 0);
}

// ========================= merged prep kernel ===============================
// bid [0,8192):    y fp32 -> yf fp16 AND yT fp16 [b][d][sy] (64x64 LDS tiles)
// bid [8192,10240): x fp32 -> xh/xl fp16 hi+lo (grid-stride)
// bid [10240,10496): W fp32 [k][n] -> WT fp16 [n][k]   (only if DOW)
template <bool DOW>
__global__ void prep_all_kernel(const float* __restrict__ y, _Float16* __restrict__ yf,
                                _Float16* __restrict__ yT, const float* __restrict__ x,
                                f16x4* __restrict__ xh, f16x4* __restrict__ xl,
                                const float* __restrict__ W, _Float16* __restrict__ WT)
{
    __shared__ _Float16 LT[64][72];
    const int tid = threadIdx.x;
    const int bid = blockIdx.x;

    if (bid < 8192) {
        const int b   = bid >> 7;
        const int rem = bid & 127;
        const int sy0 = (rem >> 4) * 64;
        const int d0  = (rem & 15) * 64;
        const int r0 = tid >> 4;
        const int c4 = (tid & 15) * 4;
        #pragma unroll
        for (int i = 0; i < 4; ++i) {
            const int r = r0 + i * 16;
            const float4 v = *(const float4*)&y[((size_t)b * 512 + sy0 + r) * 1024 + d0 + c4];
            const f16x4 hv = {(_Float16)v.x, (_Float16)v.y, (_Float16)v.z, (_Float16)v.w};
            *(f16x4*)&yf[((size_t)b * 512 + sy0 + r) * 1024 + d0 + c4] = hv;
            #pragma unroll
            for (int cc = 0; cc < 4; ++cc) {
                const int c = (cc + (tid & 3)) & 3;
                LT[c4 + c][r] = hv[c];
            }
        }
        __syncthreads();
        #pragma unroll
        for (int i = 0; i < 4; ++i) {
            const int dr = r0 + i * 16;
            const f16x4 v = *(const f16x4*)&LT[dr][(tid & 15) * 4];
            *(f16x4*)&yT[((size_t)b * 1024 + d0 + dr) * 512 + sy0 + (tid & 15) * 4] = v;
        }
    } else if (bid < 10240) {
        int i = (bid - 8192) * 256 + tid;
        const float4* in = (const float4*)x;
        for (; i < 8388608; i += 2048 * 256) {
            const float4 v = in[i];
            const _Float16 h0 = (_Float16)v.x, h1 = (_Float16)v.y,
                           h2 = (_Float16)v.z, h3 = (_Float16)v.w;
            xh[i] = (f16x4){h0, h1, h2, h3};
            xl[i] = (f16x4){(_Float16)(v.x - (float)h0), (_Float16)(v.y - (float)h1),
                            (_Float16)(v.z - (float)h2), (_Float16)(v.w - (float)h3)};
        }
    } else if constexpr (DOW) {
        const int rem = bid - 10240;
        const int k0 = (rem >> 4) * 64;
        const int n0 = (rem & 15) * 64;
        const int r0 = tid >> 4;
        const int c4 = (tid & 15) * 4;
        #pragma unroll
        for (int i = 0; i < 4; ++i) {
            const int r = r0 + i * 16;
            const float4 v = *(const float4*)&W[(size_t)(k0 + r) * 1024 + n0 + c4];
            const f16x4 hv = {(_Float16)v.x, (_Float16)v.y, (_Float16)v.z, (_Float16)v.w};
            #pragma unroll
            for (int cc = 0; cc < 4; ++cc) {
                const int c = (cc + (tid & 3)) & 3;
                LT[c4 + c][r] = hv[c];
            }
        }
        __syncthreads();
        #pragma unroll
        for (int i = 0; i < 4; ++i) {
            const int dr = r0 + i * 16;
            const f16x4 v = *(const f16x4*)&LT[dr][(tid & 15) * 4];
            *(f16x4*)&WT[(size_t)(n0 + dr) * 1024 + k0 + (tid & 15) * 4] = v;
        }
    }
}

// ===================== K1: proj = x@W + b (fp16 2-term) =====================
// 128x128 tile, BK=32, 4 waves, LDS double-buffer, ONE barrier per K-step.
// Row slot (4KB/row): per 8-half group g: h at byte g*32, l at byte g*32+16.
template <bool PRE>
__global__ __launch_bounds__(256, 3)
void proj_f16_kernel(const _Float16* __restrict__ xh, const _Float16* __restrict__ xl,
                     const _Float16* __restrict__ WT, const float* __restrict__ W,
                     const float* __restrict__ bias, char* __restrict__ outc)
{
    __shared__ _Float16 Xh[2][128][32];
    __shared__ _Float16 Xl[2][128][32];
    __shared__ _Float16 Wf[2][128][32];

    const int tid = threadIdx.x, lane = tid & 63, wave = tid >> 6;
    const int swz = (blockIdx.x & 7) * 256 + (blockIdx.x >> 3);
    const int m0 = (swz >> 3) * 128, n0 = (swz & 7) * 128;
    const int wm = (wave >> 1) * 64, wn = (wave & 1) * 64;
    const int ar = lane & 15;
    const int qs  = ((lane >> 4) ^ ((lane >> 1) & 3)) * 8;
    const int gcS = ((lane & 3) ^ ((lane >> 3) & 3)) * 8;
    const int lrow = lane >> 2;
    const int wkb = tid & 7;
    const int wn4 = (tid >> 3) * 4;

    f32x4 acc[4][4];
    #pragma unroll
    for (int i = 0; i < 4; ++i)
        #pragma unroll
        for (int j = 0; j < 4; ++j)
            acc[i][j] = (f32x4){0.f, 0.f, 0.f, 0.f};

    auto STAGE = [&](int t, int bi) {
        const int k0 = t * 32;
        #pragma unroll
        for (int tt = 0; tt < 2; ++tt) {
            const int r = wave * 32 + tt * 16 + lrow;
            async16(&xh[(size_t)(m0 + r) * 1024 + k0 + gcS], &Xh[bi][wave * 32 + tt * 16][0]);
            async16(&xl[(size_t)(m0 + r) * 1024 + k0 + gcS], &Xl[bi][wave * 32 + tt * 16][0]);
            if constexpr (PRE)
                async16(&WT[(size_t)(n0 + r) * 1024 + k0 + gcS], &Wf[bi][wave * 32 + tt * 16][0]);
        }
        if constexpr (!PRE) {
            const size_t wb = (size_t)(k0 + wkb * 4) * 1024 + n0 + wn4;
            const float4 v0 = *(const float4*)&W[wb];
            const float4 v1 = *(const float4*)&W[wb + 1024];
            const float4 v2 = *(const float4*)&W[wb + 2048];
            const float4 v3 = *(const float4*)&W[wb + 3072];
            const float rv[4][4] = {{v0.x, v0.y, v0.z, v0.w},
                                    {v1.x, v1.y, v1.z, v1.w},
                                    {v2.x, v2.y, v2.z, v2.w},
                                    {v3.x, v3.y, v3.z, v3.w}};
            #pragma unroll
            for (int j = 0; j < 4; ++j) {
                const int R = wn4 + j;
                const f16x4 hv = {(_Float16)rv[0][j], (_Float16)rv[1][j],
                                  (_Float16)rv[2][j], (_Float16)rv[3][j]};
                const int c = (wkb >> 1) ^ ((R >> 1) & 3);
                *(f16x4*)&Wf[bi][R][c * 8 + (wkb & 1) * 4] = hv;
            }
        }
    };

    STAGE(0, 0);
    __syncthreads();

    for (int t = 0; t < 32; ++t) {
        const int cur = t & 1;
        if (t < 31) STAGE(t + 1, cur ^ 1);
        f16x8 ah[4], al[4], bf[4];
        #pragma unroll
        for (int f = 0; f < 4; ++f) {
            ah[f] = *(const f16x8*)&Xh[cur][wm + f * 16 + ar][qs];
            al[f] = *(const f16x8*)&Xl[cur][wm + f * 16 + ar][qs];
            bf[f] = *(const f16x8*)&Wf[cur][wn + f * 16 + ar][qs];
        }
        #pragma unroll
        for (int i = 0; i < 4; ++i)
            #pragma unroll
            for (int j = 0; j < 4; ++j) {
                acc[i][j] = MFMA_F16(ah[i], bf[j], acc[i][j]);
                acc[i][j] = MFMA_F16(al[i], bf[j], acc[i][j]);
            }
        __syncthreads();
    }

    // epilogue: +bias, h/l interleaved per 8-half group
    const int q4 = (lane >> 4) * 4;
    #pragma unroll
    for (int j = 0; j < 4; ++j) {
        const int n = n0 + wn + j * 16 + ar;
        const float bv = bias[n];
        const int hidx = (n >> 3) * 16 + (n & 7);
        #pragma unroll
        for (int i = 0; i < 4; ++i)
            #pragma unroll
            for (int r = 0; r < 4; ++r) {
                const int R = m0 + wm + i * 16 + q4 + r;
                const float v = acc[i][j][r] + bv;
                const _Float16 h = (_Float16)v;
                const _Float16 l = (_Float16)(v - (float)h);
                _Float16* rowp = (_Float16*)(outc + (size_t)R * 4096);
                rowp[hidx] = h;
                rowp[hidx + 8] = l;
            }
    }
}

// ================= K2: attention per (batch, 64 sx rows), fp16 ==============
// Phase 0: col-split waves, LDS stripe dbuf via async16 + WAIT_VM(16) counted,
// A-regs depth-2. Phase 1: cross-wave softmax. Phase 2: B0/B1 named-reg
// rotation + WAIT_VM(8). LDS 68608B -> 2 blocks/CU.
__global__ __launch_bounds__(256, 2)
void attn_f16_kernel(const _Float16* __restrict__ yf, const _Float16* __restrict__ yT,
                     char* __restrict__ outc)
{
    __shared__ __align__(16) char smem[68608];
    _Float16 (*Yb0)[32]   = (_Float16(*)[32])smem;            // [512][32] phase 0 buf0
    _Float16 (*Yb1)[32]   = (_Float16(*)[32])(smem + 32768);  // [512][32] phase 0 buf1
    _Float16 (*Pbuf)[520] = (_Float16(*)[520])smem;           // [64][520] ph 1/2 (overlay)
    float*    Red         = (float*)(smem + 66560);           // [512] (outside overlay)

    const int tid = threadIdx.x, lane = tid & 63, wave = tid >> 6;
    const int swzb = (blockIdx.x & 7) * 64 + (blockIdx.x >> 3);
    const int b = swzb >> 3, sx0 = (swzb & 7) * 64;
    const int pbase = b * 512 + sx0;
    const int ar = lane & 15, q = lane >> 4, qk = q * 8;
    const int qs  = (q ^ ((lane >> 1) & 3)) * 8;              // swizzled frag col
    const int gcS = ((lane & 3) ^ ((lane >> 3) & 3)) * 8;     // swizzled stage col
    const int lrow = lane >> 2;
    const size_t ybase = (size_t)b * 512 * 1024;

    // ---- phase 0: S = proj @ y^T, wave w -> sy cols [128w, 128w+128) ----
    f32x4 s2[4][8];
    #pragma unroll
    for (int ri = 0; ri < 4; ++ri)
        #pragma unroll
        for (int t = 0; t < 8; ++t)
            s2[ri][t] = (f32x4){0.f, 0.f, 0.f, 0.f};

    const char* aptr = outc + (size_t)(pbase + ar) * 4096;    // + ri*65536

    auto STAGE0 = [&](int kk, _Float16 (*Yb)[32]) {           // 8 async16
        const int k0 = kk * 32;
        #pragma unroll
        for (int t = 0; t < 8; ++t) {
            const int r = wave * 128 + t * 16 + lrow;
            async16(&yf[ybase + (size_t)r * 1024 + k0 + gcS], &Yb[wave * 128 + t * 16][0]);
        }
    };
    f16x8 A0H[4], A0L[4], A1H[4], A1L[4];
    auto LOADA = [&](int kk, f16x8 (&AH)[4], f16x8 (&AL)[4]) {  // 8 loads
        #pragma unroll
        for (int ri = 0; ri < 4; ++ri) {
            const char* p = aptr + (size_t)ri * 65536 + (size_t)(kk * 4 + q) * 32;
            AH[ri] = *(const f16x8*)p;
            AL[ri] = *(const f16x8*)(p + 16);
        }
    };
    auto HALF = [&](int kk, f16x8 (&AH)[4], f16x8 (&AL)[4], _Float16 (*Yb)[32], bool more) {
        f16x8 bf[8];
        #pragma unroll
        for (int t = 0; t < 8; ++t)
            bf[t] = *(const f16x8*)&Yb[wave * 128 + t * 16 + ar][qs];
        #pragma unroll
        for (int ri = 0; ri < 4; ++ri)
            #pragma unroll
            for (int t = 0; t < 8; ++t)
                s2[ri][t] = MFMA_F16(AH[ri], bf[t], s2[ri][t]);
        #pragma unroll
        for (int ri = 0; ri < 4; ++ri)
            #pragma unroll
            for (int t = 0; t < 8; ++t)
                s2[ri][t] = MFMA_F16(AL[ri], bf[t], s2[ri][t]);
        if (more) {                 // refill the regs/buffer just consumed
            LOADA(kk + 2, AH, AL);
            STAGE0(kk + 2, Yb);
        }
    };

    // prologue: 32 vmem in flight = {s0, A0, A1, s1}
    STAGE0(0, Yb0);
    LOADA(0, A0H, A0L);
    LOADA(1, A1H, A1L);
    STAGE0(1, Yb1);

    for (int kk = 0; kk < 30; kk += 2) {
        WAIT_VM(16);                       // drains s(kk), A(kk); leaves 16 newest
        HALF(kk, A0H, A0L, Yb0, true);
        WAIT_VM(16);                       // drains s(kk+1), A(kk+1)
        HALF(kk + 1, A1H, A1L, Yb1, true);
    }
    WAIT_VM(16);
    HALF(30, A0H, A0L, Yb0, false);
    WAIT_VM(0);
    HALF(31, A1H, A1L, Yb1, false);

    // ---- phase 1: softmax, cross-wave combine via Red ----
    float pm[4][4];
    #pragma unroll
    for (int ri = 0; ri < 4; ++ri)
        #pragma unroll
        for (int r = 0; r < 4; ++r) {
            float m = -3.0e38f;
            #pragma unroll
            for (int t = 0; t < 8; ++t) m = fmaxf(m, s2[ri][t][r]);
            pm[ri][r] = m;
        }
    #pragma unroll
    for (int off = 1; off < 16; off <<= 1)
        #pragma unroll
        for (int ri = 0; ri < 4; ++ri)
            #pragma unroll
            for (int r = 0; r < 4; ++r)
                pm[ri][r] = fmaxf(pm[ri][r], __shfl_xor(pm[ri][r], off, 64));
    if (ar == 0) {
        #pragma unroll
        for (int ri = 0; ri < 4; ++ri)
            #pragma unroll
            for (int r = 0; r < 4; ++r)
                Red[wave * 64 + ri * 16 + q * 4 + r] = pm[ri][r];
    }
    __syncthreads();   // (1) also: every wave past its phase-0 LDS reads
    float gm[4][4];
    #pragma unroll
    for (int ri = 0; ri < 4; ++ri)
        #pragma unroll
        for (int r = 0; r < 4; ++r) {
            const int row = ri * 16 + q * 4 + r;
            gm[ri][r] = fmaxf(fmaxf(Red[row], Red[64 + row]),
                              fmaxf(Red[128 + row], Red[192 + row]));
        }
    float ps[4][4];
    #pragma unroll
    for (int ri = 0; ri < 4; ++ri)
        #pragma unroll
        for (int r = 0; r < 4; ++r) {
            float sum = 0.f;
            #pragma unroll
            for (int t = 0; t < 8; ++t) {
                const float e = __expf(s2[ri][t][r] - gm[ri][r]);
                s2[ri][t][r] = e;
                sum += e;
            }
            ps[ri][r] = sum;
        }
    #pragma unroll
    for (int off = 1; off < 16; off <<= 1)
        #pragma unroll
        for (int ri = 0; ri < 4; ++ri)
            #pragma unroll
            for (int r = 0; r < 4; ++r)
                ps[ri][r] += __shfl_xor(ps[ri][r], off, 64);
    if (ar == 0) {
        #pragma unroll
        for (int ri = 0; ri < 4; ++ri)
            #pragma unroll
            for (int r = 0; r < 4; ++r)
                Red[256 + wave * 64 + ri * 16 + q * 4 + r] = ps[ri][r];
    }
    __syncthreads();   // (2) all waves done with Yb region -> Pbuf write safe
    float inv[4][4];
    #pragma unroll
    for (int ri = 0; ri < 4; ++ri)
        #pragma unroll
        for (int r = 0; r < 4; ++r) {
            const int row = 256 + ri * 16 + q * 4 + r;
            inv[ri][r] = 1.0f / (Red[row] + Red[64 + row] + Red[128 + row] + Red[192 + row]);
        }
    #pragma unroll
    for (int ri = 0; ri < 4; ++ri)
        #pragma unroll
        for (int t = 0; t < 8; ++t)
            #pragma unroll
            for (int r = 0; r < 4; ++r)
                Pbuf[ri * 16 + q * 4 + r][wave * 128 + t * 16 + ar]
                    = (_Float16)(s2[ri][t][r] * inv[ri][r]);

    // phase-2 B prologue issued before the barrier (overlaps with it)
    f16x8 B0[8], B1[8];
    auto LOADB = [&](int kkf, f16x8 (&Bv)[8]) {   // 8 loads; kkf = dc*16 + kkl
        const int dc = kkf >> 4, kkl = kkf & 15;
        #pragma unroll
        for (int t = 0; t < 8; ++t)
            Bv[t] = *(const f16x8*)&yT[((size_t)b * 1024 + wave * 256 + dc * 128
                                        + t * 16 + ar) * 512 + kkl * 32 + qk];
    };
    LOADB(0, B0);
    LOADB(1, B1);
    __syncthreads();   // (3) Pbuf complete before phase-2 reads

    // ---- phase 2: O = P @ y via yT; wave w -> d cols [w*256, +256), 2 epochs ----
    float* outF = (float*)outc;
    for (int dc = 0; dc < 2; ++dc) {
        f32x4 o2[4][8];
        #pragma unroll
        for (int ri = 0; ri < 4; ++ri)
            #pragma unroll
            for (int t = 0; t < 8; ++t)
                o2[ri][t] = (f32x4){0.f, 0.f, 0.f, 0.f};

        for (int kp = 0; kp < 16; kp += 2) {
            const int kkf = dc * 16 + kp;
            {   // even half: B0
                WAIT_VM(8);
                f16x8 a2[4];
                #pragma unroll
                for (int ri = 0; ri < 4; ++ri)
                    a2[ri] = *(const f16x8*)&Pbuf[ri * 16 + ar][kp * 32 + qk];
                #pragma unroll
                for (int ri = 0; ri < 4; ++ri)
                    #pragma unroll
                    for (int t = 0; t < 8; ++t)
                        o2[ri][t] = MFMA_F16(a2[ri], B0[t], o2[ri][t]);
                if (kkf + 2 < 32) LOADB(kkf + 2, B0);
            }
            {   // odd half: B1
                if (kkf + 1 == 31) { WAIT_VM(0); } else { WAIT_VM(8); }
                f16x8 a2[4];
                #pragma unroll
                for (int ri = 0; ri < 4; ++ri)
                    a2[ri] = *(const f16x8*)&Pbuf[ri * 16 + ar][(kp + 1) * 32 + qk];
                #pragma unroll
                for (int ri = 0; ri < 4; ++ri)
                    #pragma unroll
                    for (int t = 0; t < 8; ++t)
                        o2[ri][t] = MFMA_F16(a2[ri], B1[t], o2[ri][t]);
                if (kkf + 3 < 32) LOADB(kkf + 3, B1);
            }
        }
        #pragma unroll
        for (int ri = 0; ri < 4; ++ri)
            #pragma unroll
            for (int t = 0; t < 8; ++t)
                #pragma unroll
                for (int r = 0; r < 4; ++r)
                    outF[(size_t)(pbase + ri * 16 + q * 4 + r) * 1024
                         + wave * 256 + dc * 128 + t * 16 + ar] = o2[ri][t][r];
    }
}

// ===================== fallback path (round-1, known good) ==================

__device__ __forceinline__ void cvt4(const float4 v, bf16x4& h, bf16x4& l) {
    const float f0 = v.x, f1 = v.y, f2 = v.z, f3 = v.w;
    const __bf16 h0 = (__bf16)f0, h1 = (__bf16)f1, h2 = (__bf16)f2, h3 = (__bf16)f3;
    h = (bf16x4){h0, h1, h2, h3};
    l = (bf16x4){(__bf16)(f0 - (float)h0), (__bf16)(f1 - (float)h1),
                 (__bf16)(f2 - (float)h2), (__bf16)(f3 - (float)h3)};
}

__global__ __launch_bounds__(256, 2)
void proj_kernel_fb(const float* __restrict__ x, const float* __restrict__ W,
                    const float* __restrict__ bias, float* __restrict__ proj)
{
    __shared__ __bf16 Ah[128][40];
    __shared__ __bf16 Al[128][40];
    __shared__ __bf16 Bh[128][40];
    __shared__ __bf16 Bl[128][40];

    const int tid = threadIdx.x, lane = tid & 63, wave = tid >> 6;
    const int wm = (wave >> 1) * 64, wn = (wave & 1) * 64;
    const int m0 = (blockIdx.x >> 3) * 128, n0 = (blockIdx.x & 7) * 128;
    const int ar = lane & 15, ak = (lane >> 4) * 8;

    f32x4 acc[4][4];
    #pragma unroll
    for (int i = 0; i < 4; ++i)
        #pragma unroll
        for (int j = 0; j < 4; ++j)
            acc[i][j] = (f32x4){0.f, 0.f, 0.f, 0.f};

    const int xr = tid >> 3, xc = (tid & 7) * 4;
    const int wkb = tid >> 5, wn4 = (tid & 31) * 4;

    for (int k0 = 0; k0 < 1024; k0 += 32) {
        __syncthreads();
        #pragma unroll
        for (int it = 0; it < 4; ++it) {
            const int r = xr + it * 32;
            const float4 v = *(const float4*)&x[(size_t)(m0 + r) * 1024 + k0 + xc];
            bf16x4 h, l; cvt4(v, h, l);
            *(bf16x4*)&Ah[r][xc] = h;
            *(bf16x4*)&Al[r][xc] = l;
        }
        {
            const size_t wb = (size_t)(k0 + wkb * 4) * 1024 + n0 + wn4;
            const float4 v0 = *(const float4*)&W[wb];
            const float4 v1 = *(const float4*)&W[wb + 1024];
            const float4 v2 = *(const float4*)&W[wb + 2048];
            const float4 v3 = *(const float4*)&W[wb + 3072];
            const float rv[4][4] = {{v0.x, v0.y, v0.z, v0.w},
                                    {v1.x, v1.y, v1.z, v1.w},
                                    {v2.x, v2.y, v2.z, v2.w},
                                    {v3.x, v3.y, v3.z, v3.w}};
            #pragma unroll
            for (int j = 0; j < 4; ++j) {
                bf16x4 h, l;
                #pragma unroll
                for (int kk = 0; kk < 4; ++kk) {
                    const float f = rv[kk][j];
                    const __bf16 hb = (__bf16)f;
                    h[kk] = hb;
                    l[kk] = (__bf16)(f - (float)hb);
                }
                *(bf16x4*)&Bh[wn4 + j][wkb * 4] = h;
                *(bf16x4*)&Bl[wn4 + j][wkb * 4] = l;
            }
        }
        __syncthreads();

        bf16x8 a_h[4], a_l[4], b_h[4], b_l[4];
        #pragma unroll
        for (int f = 0; f < 4; ++f) {
            a_h[f] = *(const bf16x8*)&Ah[wm + f * 16 + ar][ak];
            a_l[f] = *(const bf16x8*)&Al[wm + f * 16 + ar][ak];
            b_h[f] = *(const bf16x8*)&Bh[wn + f * 16 + ar][ak];
            b_l[f] = *(const bf16x8*)&Bl[wn + f * 16 + ar][ak];
        }
        #pragma unroll
        for (int i = 0; i < 4; ++i)
            #pragma unroll
            for (int j = 0; j < 4; ++j) {
                acc[i][j] = MFMA_BF16(a_h[i], b_h[j], acc[i][j]);
                acc[i][j] = MFMA_BF16(a_l[i], b_h[j], acc[i][j]);
                acc[i][j] = MFMA_BF16(a_h[i], b_l[j], acc[i][j]);
            }
    }

    const int q4 = (lane >> 4) * 4;
    #pragma unroll
    for (int j = 0; j < 4; ++j) {
        const int n = n0 + wn + j * 16 + ar;
        const float bv = bias[n];
        #pragma unroll
        for (int i = 0; i < 4; ++i) {
            const size_t base = (size_t)(m0 + wm + i * 16 + q4) * 1024 + n;
            #pragma unroll
            for (int r = 0; r < 4; ++r)
                proj[base + (size_t)r * 1024] = acc[i][j][r] + bv;
        }
    }
}

__global__ __launch_bounds__(256, 1)
void attn_kernel_fb(const float* __restrict__ y, float* __restrict__ out)
{
    __shared__ __bf16 Ph[64][40];
    __shared__ __bf16 Pl[64][40];
    __shared__ __bf16 Yh[128][40];
    __shared__ __bf16 Yl[128][40];
    __shared__ __bf16 Pbuf[64][520];

    const int tid = threadIdx.x, lane = tid & 63, wave = tid >> 6;
    const int b = blockIdx.x >> 3, sx0 = (blockIdx.x & 7) * 64;
    const size_t ybase = (size_t)b * 512 * 1024;
    const size_t pbase = ((size_t)b * 512 + sx0) * 1024;
    const int ar = lane & 15, ak = (lane >> 4) * 8, q = lane >> 4;

    f32x4 s[4][8];
    #pragma unroll
    for (int nb = 0; nb < 4; ++nb)
        #pragma unroll
        for (int f = 0; f < 8; ++f)
            s[nb][f] = (f32x4){0.f, 0.f, 0.f, 0.f};

    const int pr = tid >> 3, pc = (tid & 7) * 4;

    for (int k0 = 0; k0 < 1024; k0 += 32) {
        __syncthreads();
        #pragma unroll
        for (int it = 0; it < 2; ++it) {
            const int r = pr + it * 32;
            const float4 v = *(const float4*)&out[pbase + (size_t)r * 1024 + k0 + pc];
            bf16x4 h, l; cvt4(v, h, l);
            *(bf16x4*)&Ph[r][pc] = h;
            *(bf16x4*)&Pl[r][pc] = l;
        }
        #pragma unroll
        for (int nb = 0; nb < 4; ++nb) {
            if (nb) __syncthreads();
            const int sy0 = nb * 128;
            #pragma unroll
            for (int it = 0; it < 4; ++it) {
                const int r = pr + it * 32;
                const float4 v = *(const float4*)&y[ybase + (size_t)(sy0 + r) * 1024 + k0 + pc];
                bf16x4 h, l; cvt4(v, h, l);
                *(bf16x4*)&Yh[r][pc] = h;
                *(bf16x4*)&Yl[r][pc] = l;
            }
            __syncthreads();
            const bf16x8 a_h = *(const bf16x8*)&Ph[wave * 16 + ar][ak];
            const bf16x8 a_l = *(const bf16x8*)&Pl[wave * 16 + ar][ak];
            #pragma unroll
            for (int f = 0; f < 8; ++f) {
                const bf16x8 b_h = *(const bf16x8*)&Yh[f * 16 + ar][ak];
                const bf16x8 b_l = *(const bf16x8*)&Yl[f * 16 + ar][ak];
                s[nb][f] = MFMA_BF16(a_h, b_h, s[nb][f]);
                s[nb][f] = MFMA_BF16(a_l, b_h, s[nb][f]);
                s[nb][f] = MFMA_BF16(a_h, b_l, s[nb][f]);
            }
        }
    }

    #pragma unroll
    for (int r = 0; r < 4; ++r) {
        float m = -3.0e38f;
        #pragma unroll
        for (int nb = 0; nb < 4; ++nb)
            #pragma unroll
            for (int f = 0; f < 8; ++f)
                m = fmaxf(m, s[nb][f][r]);
        #pragma unroll
        for (int off = 1; off < 16; off <<= 1)
            m = fmaxf(m, __shfl_xor(m, off, 64));
        float sum = 0.f;
        #pragma unroll
        for (int nb = 0; nb < 4; ++nb)
            #pragma unroll
            for (int f = 0; f < 8; ++f) {
                const float e = __expf(s[nb][f][r] - m);
                s[nb][f][r] = e;
                sum += e;
            }
        #pragma unroll
        for (int off = 1; off < 16; off <<= 1)
            sum += __shfl_xor(sum, off, 64);
        const float inv = 1.0f / sum;
        #pragma unroll
        for (int nb = 0; nb < 4; ++nb)
            #pragma unroll
            for (int f = 0; f < 8; ++f)
                s[nb][f][r] *= inv;
    }
    #pragma unroll
    for (int nb = 0; nb < 4; ++nb)
        #pragma unroll
        for (int f = 0; f < 8; ++f)
            #pragma unroll
            for (int r = 0; r < 4; ++r)
                Pbuf[wave * 16 + q * 4 + r][nb * 128 + f * 16 + ar] = (__bf16)s[nb][f][r];

    const int y2kb = tid >> 5, y2n4 = (tid & 31) * 4;
    for (int d0 = 0; d0 < 1024; d0 += 128) {
        f32x4 o[8];
        #pragma unroll
        for (int f = 0; f < 8; ++f) o[f] = (f32x4){0.f, 0.f, 0.f, 0.f};

        for (int k0 = 0; k0 < 512; k0 += 32) {
            __syncthreads();
            const size_t yb = ybase + (size_t)(k0 + y2kb * 4) * 1024 + d0 + y2n4;
            const float4 v0 = *(const float4*)&y[yb];
            const float4 v1 = *(const float4*)&y[yb + 1024];
            const float4 v2 = *(const float4*)&y[yb + 2048];
            const float4 v3 = *(const float4*)&y[yb + 3072];
            const float rv[4][4] = {{v0.x, v0.y, v0.z, v0.w},
                                    {v1.x, v1.y, v1.z, v1.w},
                                    {v2.x, v2.y, v2.z, v2.w},
                                    {v3.x, v3.y, v3.z, v3.w}};
            #pragma unroll
            for (int j = 0; j < 4; ++j) {
                const bf16x4 h = (bf16x4){(__bf16)rv[0][j], (__bf16)rv[1][j],
                                          (__bf16)rv[2][j], (__bf16)rv[3][j]};
                *(bf16x4*)&Yh[y2n4 + j][y2kb * 4] = h;
            }
            __syncthreads();
            const bf16x8 a = *(const bf16x8*)&Pbuf[wave * 16 + ar][k0 + ak];
            #pragma unroll
            for (int f = 0; f < 8; ++f) {
                const bf16x8 bb = *(const bf16x8*)&Yh[f * 16 + ar][ak];
                o[f] = MFMA_BF16(a, bb, o[f]);
            }
        }
        #pragma unroll
        for (int f = 0; f < 8; ++f)
            #pragma unroll
            for (int r = 0; r < 4; ++r)
                out[pbase + (size_t)(wave * 16 + q * 4 + r) * 1024 + d0 + f * 16 + ar] = o[f][r];
    }
}

// ============================== launch ======================================

extern "C" void kernel_launch(void* const* d_in, const int* in_sizes, int n_in,
                              void* d_out, int out_size, void* d_ws, size_t ws_size,
                              hipStream_t stream) {
    (void)in_sizes; (void)n_in; (void)out_size;
    const float* x    = (const float*)d_in[0];
    const float* y    = (const float*)d_in[1];
    const float* W    = (const float*)d_in[2];
    const float* bias = (const float*)d_in[3];

    if (ws_size >= 268435456ULL) {
        _Float16* yf = (_Float16*)d_ws;
        _Float16* yT = yf + 33554432;
        _Float16* xh = yT + 33554432;
        _Float16* xl = xh + 33554432;
        _Float16* WT = xl + 33554432;
        const bool pre = ws_size >= 268435456ULL + 2097152ULL;

        if (pre) {
            prep_all_kernel<true><<<dim3(10496), dim3(256), 0, stream>>>(
                y, yf, yT, x, (f16x4*)xh, (f16x4*)xl, W, WT);
            proj_f16_kernel<true><<<dim3(2048), dim3(256), 0, stream>>>(xh, xl, WT, W, bias,
                                                                        (char*)d_out);
        } else {
            prep_all_kernel<false><<<dim3(10240), dim3(256), 0, stream>>>(
                y, yf, yT, x, (f16x4*)xh, (f16x4*)xl, W, nullptr);
            proj_f16_kernel<false><<<dim3(2048), dim3(256), 0, stream>>>(xh, xl, nullptr, W,
                                                                         bias, (char*)d_out);
        }
        attn_f16_kernel<<<dim3(512), dim3(256), 0, stream>>>(yf, yT, (char*)d_out);
    } else {
        float* out = (float*)d_out;
        proj_kernel_fb<<<dim3(256 * 8), dim3(256), 0, stream>>>(x, W, bias, out);
        attn_kernel_fb<<<dim3(64 * 8), dim3(256), 0, stream>>>(y, out);
    }
}

// Round 6
// 693.349 us; speedup vs baseline: 1.1181x; 1.1181x over previous
//
#include <hip/hip_runtime.h>

// ESIM layer: out = softmax((x@W + b) @ y^T) @ y
// B=64, Sx=Sy=512, D=1024, fp32 in/out.
//
// Round-7:
//  * attn: reverted EXACTLY to the R4 kernel (218us, no spill). R5's B0/B1
//    prefetch spilled ~1KB/thread (WRITE +139MB) -- register budget there is
//    saturated; do not add VGPR-cost prefetch to attn.
//  * proj: T3/T4 counted-vmcnt pipeline. Triple-buffer LDS (3x24KB=72KB,
//    2 blk/CU), raw s_barrier + WAIT_VM(12) (never 0 mid-loop), stage->use
//    distance 3 K-steps (~HBM latency). Epilogue assembles h/l row segments
//    in LDS then does coalesced 16B stores (was 128 scalar 2B stores/thread).
//  * prep: merged single kernel (R5), unchanged.

typedef float  f32x4  __attribute__((ext_vector_type(4)));
typedef _Float16 f16x8 __attribute__((ext_vector_type(8)));
typedef _Float16 f16x4 __attribute__((ext_vector_type(4)));
typedef __bf16 bf16x8 __attribute__((ext_vector_type(8)));
typedef __bf16 bf16x4 __attribute__((ext_vector_type(4)));

#define MFMA_F16(a, b, c)  __builtin_amdgcn_mfma_f32_16x16x32_f16((a), (b), (c), 0, 0, 0)
#define MFMA_BF16(a, b, c) __builtin_amdgcn_mfma_f32_16x16x32_bf16((a), (b), (c), 0, 0, 0)

#define WAIT_VM(N)  do { asm volatile("s_waitcnt vmcnt(" #N ")" ::: "memory"); \
                         __builtin_amdgcn_sched_barrier(0); } while (0)

__device__ __forceinline__ void async16(const void* g, void* lds) {
    __builtin_amdgcn_global_load_lds(
        (const __attribute__((address_space(1))) unsigned int*)g,
        (__attribute__((address_space(3))) unsigned int*)lds, 16, 0, 0);
}

// ========================= merged prep kernel ===============================
// bid [0,8192):    y fp32 -> yf fp16 AND yT fp16 [b][d][sy] (64x64 LDS tiles)
// bid [8192,10240): x fp32 -> xh/xl fp16 hi+lo (grid-stride)
// bid [10240,10496): W fp32 [k][n] -> WT fp16 [n][k]   (only if DOW)
template <bool DOW>
__global__ void prep_all_kernel(const float* __restrict__ y, _Float16* __restrict__ yf,
                                _Float16* __restrict__ yT, const float* __restrict__ x,
                                f16x4* __restrict__ xh, f16x4* __restrict__ xl,
                                const float* __restrict__ W, _Float16* __restrict__ WT)
{
    __shared__ _Float16 LT[64][72];
    const int tid = threadIdx.x;
    const int bid = blockIdx.x;

    if (bid < 8192) {
        const int b   = bid >> 7;
        const int rem = bid & 127;
        const int sy0 = (rem >> 4) * 64;
        const int d0  = (rem & 15) * 64;
        const int r0 = tid >> 4;
        const int c4 = (tid & 15) * 4;
        #pragma unroll
        for (int i = 0; i < 4; ++i) {
            const int r = r0 + i * 16;
            const float4 v = *(const float4*)&y[((size_t)b * 512 + sy0 + r) * 1024 + d0 + c4];
            const f16x4 hv = {(_Float16)v.x, (_Float16)v.y, (_Float16)v.z, (_Float16)v.w};
            *(f16x4*)&yf[((size_t)b * 512 + sy0 + r) * 1024 + d0 + c4] = hv;
            #pragma unroll
            for (int cc = 0; cc < 4; ++cc) {
                const int c = (cc + (tid & 3)) & 3;
                LT[c4 + c][r] = hv[c];
            }
        }
        __syncthreads();
        #pragma unroll
        for (int i = 0; i < 4; ++i) {
            const int dr = r0 + i * 16;
            const f16x4 v = *(const f16x4*)&LT[dr][(tid & 15) * 4];
            *(f16x4*)&yT[((size_t)b * 1024 + d0 + dr) * 512 + sy0 + (tid & 15) * 4] = v;
        }
    } else if (bid < 10240) {
        int i = (bid - 8192) * 256 + tid;
        const float4* in = (const float4*)x;
        for (; i < 8388608; i += 2048 * 256) {
            const float4 v = in[i];
            const _Float16 h0 = (_Float16)v.x, h1 = (_Float16)v.y,
                           h2 = (_Float16)v.z, h3 = (_Float16)v.w;
            xh[i] = (f16x4){h0, h1, h2, h3};
            xl[i] = (f16x4){(_Float16)(v.x - (float)h0), (_Float16)(v.y - (float)h1),
                            (_Float16)(v.z - (float)h2), (_Float16)(v.w - (float)h3)};
        }
    } else if constexpr (DOW) {
        const int rem = bid - 10240;
        const int k0 = (rem >> 4) * 64;
        const int n0 = (rem & 15) * 64;
        const int r0 = tid >> 4;
        const int c4 = (tid & 15) * 4;
        #pragma unroll
        for (int i = 0; i < 4; ++i) {
            const int r = r0 + i * 16;
            const float4 v = *(const float4*)&W[(size_t)(k0 + r) * 1024 + n0 + c4];
            const f16x4 hv = {(_Float16)v.x, (_Float16)v.y, (_Float16)v.z, (_Float16)v.w};
            #pragma unroll
            for (int cc = 0; cc < 4; ++cc) {
                const int c = (cc + (tid & 3)) & 3;
                LT[c4 + c][r] = hv[c];
            }
        }
        __syncthreads();
        #pragma unroll
        for (int i = 0; i < 4; ++i) {
            const int dr = r0 + i * 16;
            const f16x4 v = *(const f16x4*)&LT[dr][(tid & 15) * 4];
            *(f16x4*)&WT[(size_t)(n0 + dr) * 1024 + k0 + (tid & 15) * 4] = v;
        }
    }
}

// ===================== K1: proj = x@W + b (fp16 2-term) =====================
// 128x128 tile, BK=32, 4 waves. Triple-buffer LDS + raw s_barrier + counted
// vmcnt (tile in flight depth 3; vmcnt(12) leaves 2 newest tiles pending).
// Row slot (4KB/row): per 8-half group g: h at byte g*32, l at g*32+16.
template <bool PRE>
__global__ __launch_bounds__(256, 2)
void proj_f16_kernel(const _Float16* __restrict__ xh, const _Float16* __restrict__ xl,
                     const _Float16* __restrict__ WT, const float* __restrict__ W,
                     const float* __restrict__ bias, char* __restrict__ outc)
{
    __shared__ __align__(16) char psm[73728];   // 3 bufs x (Xh 8K | Xl 8K | Wf 8K)

    const int tid = threadIdx.x, lane = tid & 63, wave = tid >> 6;
    const int swz = (blockIdx.x & 7) * 256 + (blockIdx.x >> 3);
    const int m0 = (swz >> 3) * 128, n0 = (swz & 7) * 128;
    const int wm = (wave >> 1) * 64, wn = (wave & 1) * 64;
    const int ar = lane & 15;
    const int qs  = ((lane >> 4) ^ ((lane >> 1) & 3)) * 8;
    const int gcS = ((lane & 3) ^ ((lane >> 3) & 3)) * 8;
    const int lrow = lane >> 2;
    const int wkb = tid & 7;
    const int wn4 = (tid >> 3) * 4;

    f32x4 acc[4][4];
    #pragma unroll
    for (int i = 0; i < 4; ++i)
        #pragma unroll
        for (int j = 0; j < 4; ++j)
            acc[i][j] = (f32x4){0.f, 0.f, 0.f, 0.f};

    auto STAGE = [&](int t, int bi) {
        const int k0 = t * 32;
        _Float16 (*Xh)[32] = (_Float16(*)[32])(psm + bi * 24576);
        _Float16 (*Xl)[32] = (_Float16(*)[32])(psm + bi * 24576 + 8192);
        _Float16 (*Wf)[32] = (_Float16(*)[32])(psm + bi * 24576 + 16384);
        #pragma unroll
        for (int tt = 0; tt < 2; ++tt) {
            const int r = wave * 32 + tt * 16 + lrow;
            async16(&xh[(size_t)(m0 + r) * 1024 + k0 + gcS], &Xh[wave * 32 + tt * 16][0]);
            async16(&xl[(size_t)(m0 + r) * 1024 + k0 + gcS], &Xl[wave * 32 + tt * 16][0]);
            if constexpr (PRE)
                async16(&WT[(size_t)(n0 + r) * 1024 + k0 + gcS], &Wf[wave * 32 + tt * 16][0]);
        }
        if constexpr (!PRE) {
            const size_t wb = (size_t)(k0 + wkb * 4) * 1024 + n0 + wn4;
            const float4 v0 = *(const float4*)&W[wb];
            const float4 v1 = *(const float4*)&W[wb + 1024];
            const float4 v2 = *(const float4*)&W[wb + 2048];
            const float4 v3 = *(const float4*)&W[wb + 3072];
            const float rv[4][4] = {{v0.x, v0.y, v0.z, v0.w},
                                    {v1.x, v1.y, v1.z, v1.w},
                                    {v2.x, v2.y, v2.z, v2.w},
                                    {v3.x, v3.y, v3.z, v3.w}};
            #pragma unroll
            for (int j = 0; j < 4; ++j) {
                const int R = wn4 + j;
                const f16x4 hv = {(_Float16)rv[0][j], (_Float16)rv[1][j],
                                  (_Float16)rv[2][j], (_Float16)rv[3][j]};
                const int c = (wkb >> 1) ^ ((R >> 1) & 3);
                *(f16x4*)&Wf[R][c * 8 + (wkb & 1) * 4] = hv;
            }
        }
    };

    // prologue: 3 tiles in flight
    STAGE(0, 0);
    STAGE(1, 1);
    STAGE(2, 2);

    int bi = 0;
    for (int t = 0; t < 32; ++t) {
        // wait own tile-t asyncs (FIFO: leave 2 newest tiles = 12/8 pending)
        if (t < 30)       { if constexpr (PRE) WAIT_VM(12); else WAIT_VM(8); }
        else if (t == 30) { if constexpr (PRE) WAIT_VM(6);  else WAIT_VM(4); }
        else              { WAIT_VM(0); }
        __builtin_amdgcn_s_barrier();   // rendezvous: everyone's tile-t landed

        _Float16 (*Xh)[32] = (_Float16(*)[32])(psm + bi * 24576);
        _Float16 (*Xl)[32] = (_Float16(*)[32])(psm + bi * 24576 + 8192);
        _Float16 (*Wf)[32] = (_Float16(*)[32])(psm + bi * 24576 + 16384);
        f16x8 ah[4], al[4], bfv[4];
        #pragma unroll
        for (int f = 0; f < 4; ++f) {
            ah[f]  = *(const f16x8*)&Xh[wm + f * 16 + ar][qs];
            al[f]  = *(const f16x8*)&Xl[wm + f * 16 + ar][qs];
            bfv[f] = *(const f16x8*)&Wf[wn + f * 16 + ar][qs];
        }
        #pragma unroll
        for (int i = 0; i < 4; ++i)
            #pragma unroll
            for (int j = 0; j < 4; ++j) {
                acc[i][j] = MFMA_F16(ah[i], bfv[j], acc[i][j]);
                acc[i][j] = MFMA_F16(al[i], bfv[j], acc[i][j]);
            }
        __builtin_amdgcn_s_barrier();   // all reads of buf bi done

        if (t < 29) {
            STAGE(t + 3, bi);           // refill the buffer just consumed
            if constexpr (!PRE)
                asm volatile("s_waitcnt lgkmcnt(0)" ::: "memory");  // ds_writes visible
        }
        bi = (bi == 2) ? 0 : bi + 1;
    }

    // ---- epilogue: acc -> LDS (h/l interleaved row segments) -> coalesced out
    _Float16* Ep = (_Float16*)psm;      // [128 rows][256 f16] = 512B/row
    const int q4 = (lane >> 4) * 4;
    #pragma unroll
    for (int j = 0; j < 4; ++j) {
        const int nloc = wn + j * 16 + ar;
        const float bv = bias[n0 + nloc];
        const int nidx = (nloc >> 3) * 16 + (nloc & 7);
        #pragma unroll
        for (int i = 0; i < 4; ++i)
            #pragma unroll
            for (int r = 0; r < 4; ++r) {
                const int Rl = wm + i * 16 + q4 + r;
                const float v = acc[i][j][r] + bv;
                const _Float16 h = (_Float16)v;
                Ep[Rl * 256 + nidx]     = h;
                Ep[Rl * 256 + nidx + 8] = (_Float16)(v - (float)h);
            }
    }
    __syncthreads();
    #pragma unroll
    for (int c = 0; c < 16; ++c) {
        const int lin = c * 4096 + tid * 16;
        const int row = lin >> 9;
        const int off = lin & 511;
        *(float4*)(outc + (size_t)(m0 + row) * 4096 + n0 * 4 + off)
            = *(const float4*)(psm + lin);
    }
}

// ================= K2: attention per (batch, 64 sx rows), fp16 ==============
// (R4 version, verbatim: col-split waves, no LDS staging, A depth-2 named regs)
__global__ __launch_bounds__(256, 2)
void attn_f16_kernel(const _Float16* __restrict__ yf, const _Float16* __restrict__ yT,
                     char* __restrict__ outc)
{
    __shared__ _Float16 Pbuf[64][520];
    __shared__ float    Red[512];

    const int tid = threadIdx.x, lane = tid & 63, wave = tid >> 6;
    const int swzb = (blockIdx.x & 7) * 64 + (blockIdx.x >> 3);
    const int b = swzb >> 3, sx0 = (swzb & 7) * 64;
    const int pbase = b * 512 + sx0;
    const int ar = lane & 15, q = lane >> 4, qk = q * 8;
    const size_t ybase = (size_t)b * 512 * 1024;

    // ---- phase 0: S = proj @ y^T, wave w -> sy cols [128w, 128w+128) ----
    f32x4 s2[4][8];
    #pragma unroll
    for (int ri = 0; ri < 4; ++ri)
        #pragma unroll
        for (int t = 0; t < 8; ++t)
            s2[ri][t] = (f32x4){0.f, 0.f, 0.f, 0.f};

    const char* aptr = outc + (size_t)(pbase + ar) * 4096;          // + ri*65536
    const _Float16* yw = yf + ybase + (size_t)(wave * 128 + ar) * 1024;  // + t*16384

    f16x8 A0H[4], A0L[4], A1H[4], A1L[4];
    auto LOADA = [&](int kk, f16x8 (&AH)[4], f16x8 (&AL)[4]) {
        #pragma unroll
        for (int ri = 0; ri < 4; ++ri) {
            const char* p = aptr + (size_t)ri * 65536 + (size_t)(kk * 4 + q) * 32;
            AH[ri] = *(const f16x8*)p;
            AL[ri] = *(const f16x8*)(p + 16);
        }
    };

    LOADA(0, A0H, A0L);
    LOADA(1, A1H, A1L);

    for (int kk = 0; kk < 32; kk += 2) {
        {   // even step uses A0; refill A0 <- A(kk+2) after its use
            f16x8 bf[8];
            #pragma unroll
            for (int t = 0; t < 8; ++t)
                bf[t] = *(const f16x8*)&yw[(size_t)t * 16384 + kk * 32 + qk];
            #pragma unroll
            for (int ri = 0; ri < 4; ++ri)
                #pragma unroll
                for (int t = 0; t < 8; ++t) {
                    s2[ri][t] = MFMA_F16(A0H[ri], bf[t], s2[ri][t]);
                    s2[ri][t] = MFMA_F16(A0L[ri], bf[t], s2[ri][t]);
                }
            if (kk + 2 < 32) LOADA(kk + 2, A0H, A0L);
        }
        {   // odd step uses A1; refill A1 <- A(kk+3)
            f16x8 bf[8];
            #pragma unroll
            for (int t = 0; t < 8; ++t)
                bf[t] = *(const f16x8*)&yw[(size_t)t * 16384 + (kk + 1) * 32 + qk];
            #pragma unroll
            for (int ri = 0; ri < 4; ++ri)
                #pragma unroll
                for (int t = 0; t < 8; ++t) {
                    s2[ri][t] = MFMA_F16(A1H[ri], bf[t], s2[ri][t]);
                    s2[ri][t] = MFMA_F16(A1L[ri], bf[t], s2[ri][t]);
                }
            if (kk + 3 < 32) LOADA(kk + 3, A1H, A1L);
        }
    }

    // ---- phase 1: softmax, cross-wave combine via Red ----
    float pm[4][4];
    #pragma unroll
    for (int ri = 0; ri < 4; ++ri)
        #pragma unroll
        for (int r = 0; r < 4; ++r) {
            float m = -3.0e38f;
            #pragma unroll
            for (int t = 0; t < 8; ++t) m = fmaxf(m, s2[ri][t][r]);
            pm[ri][r] = m;
        }
    #pragma unroll
    for (int off = 1; off < 16; off <<= 1)
        #pragma unroll
        for (int ri = 0; ri < 4; ++ri)
            #pragma unroll
            for (int r = 0; r < 4; ++r)
                pm[ri][r] = fmaxf(pm[ri][r], __shfl_xor(pm[ri][r], off, 64));
    if (ar == 0) {
        #pragma unroll
        for (int ri = 0; ri < 4; ++ri)
            #pragma unroll
            for (int r = 0; r < 4; ++r)
                Red[wave * 64 + ri * 16 + q * 4 + r] = pm[ri][r];
    }
    __syncthreads();
    float gm[4][4];
    #pragma unroll
    for (int ri = 0; ri < 4; ++ri)
        #pragma unroll
        for (int r = 0; r < 4; ++r) {
            const int row = ri * 16 + q * 4 + r;
            gm[ri][r] = fmaxf(fmaxf(Red[row], Red[64 + row]),
                              fmaxf(Red[128 + row], Red[192 + row]));
        }
    float ps[4][4];
    #pragma unroll
    for (int ri = 0; ri < 4; ++ri)
        #pragma unroll
        for (int r = 0; r < 4; ++r) {
            float sum = 0.f;
            #pragma unroll
            for (int t = 0; t < 8; ++t) {
                const float e = __expf(s2[ri][t][r] - gm[ri][r]);
                s2[ri][t][r] = e;
                sum += e;
            }
            ps[ri][r] = sum;
        }
    #pragma unroll
    for (int off = 1; off < 16; off <<= 1)
        #pragma unroll
        for (int ri = 0; ri < 4; ++ri)
            #pragma unroll
            for (int r = 0; r < 4; ++r)
                ps[ri][r] += __shfl_xor(ps[ri][r], off, 64);
    if (ar == 0) {
        #pragma unroll
        for (int ri = 0; ri < 4; ++ri)
            #pragma unroll
            for (int r = 0; r < 4; ++r)
                Red[256 + wave * 64 + ri * 16 + q * 4 + r] = ps[ri][r];
    }
    __syncthreads();
    float inv[4][4];
    #pragma unroll
    for (int ri = 0; ri < 4; ++ri)
        #pragma unroll
        for (int r = 0; r < 4; ++r) {
            const int row = 256 + ri * 16 + q * 4 + r;
            inv[ri][r] = 1.0f / (Red[row] + Red[64 + row] + Red[128 + row] + Red[192 + row]);
        }
    #pragma unroll
    for (int ri = 0; ri < 4; ++ri)
        #pragma unroll
        for (int t = 0; t < 8; ++t)
            #pragma unroll
            for (int r = 0; r < 4; ++r)
                Pbuf[ri * 16 + q * 4 + r][wave * 128 + t * 16 + ar]
                    = (_Float16)(s2[ri][t][r] * inv[ri][r]);
    __syncthreads();   // Pbuf complete before phase-2 reads

    // ---- phase 2: O = P @ y via yT; wave w -> d cols [w*256, +256), 2 epochs ----
    float* outF = (float*)outc;
    #pragma unroll
    for (int dc = 0; dc < 2; ++dc) {
        f32x4 o2[4][8];
        #pragma unroll
        for (int ri = 0; ri < 4; ++ri)
            #pragma unroll
            for (int t = 0; t < 8; ++t)
                o2[ri][t] = (f32x4){0.f, 0.f, 0.f, 0.f};

        const _Float16* ytw = yT + ((size_t)b * 1024 + wave * 256 + dc * 128 + ar) * 512;

        for (int kk = 0; kk < 16; ++kk) {
            f16x8 a2[4], b2[8];
            #pragma unroll
            for (int ri = 0; ri < 4; ++ri)
                a2[ri] = *(const f16x8*)&Pbuf[ri * 16 + ar][kk * 32 + qk];
            #pragma unroll
            for (int t = 0; t < 8; ++t)
                b2[t] = *(const f16x8*)&ytw[(size_t)t * 16 * 512 + kk * 32 + qk];
            #pragma unroll
            for (int ri = 0; ri < 4; ++ri)
                #pragma unroll
                for (int t = 0; t < 8; ++t)
                    o2[ri][t] = MFMA_F16(a2[ri], b2[t], o2[ri][t]);
        }
        #pragma unroll
        for (int ri = 0; ri < 4; ++ri)
            #pragma unroll
            for (int t = 0; t < 8; ++t)
                #pragma unroll
                for (int r = 0; r < 4; ++r)
                    outF[(size_t)(pbase + ri * 16 + q * 4 + r) * 1024
                         + wave * 256 + dc * 128 + t * 16 + ar] = o2[ri][t][r];
    }
}

// ===================== fallback path (round-1, known good) ==================

__device__ __forceinline__ void cvt4(const float4 v, bf16x4& h, bf16x4& l) {
    const float f0 = v.x, f1 = v.y, f2 = v.z, f3 = v.w;
    const __bf16 h0 = (__bf16)f0, h1 = (__bf16)f1, h2 = (__bf16)f2, h3 = (__bf16)f3;
    h = (bf16x4){h0, h1, h2, h3};
    l = (bf16x4){(__bf16)(f0 - (float)h0), (__bf16)(f1 - (float)h1),
                 (__bf16)(f2 - (float)h2), (__bf16)(f3 - (float)h3)};
}

__global__ __launch_bounds__(256, 2)
void proj_kernel_fb(const float* __restrict__ x, const float* __restrict__ W,
                    const float* __restrict__ bias, float* __restrict__ proj)
{
    __shared__ __bf16 Ah[128][40];
    __shared__ __bf16 Al[128][40];
    __shared__ __bf16 Bh[128][40];
    __shared__ __bf16 Bl[128][40];

    const int tid = threadIdx.x, lane = tid & 63, wave = tid >> 6;
    const int wm = (wave >> 1) * 64, wn = (wave & 1) * 64;
    const int m0 = (blockIdx.x >> 3) * 128, n0 = (blockIdx.x & 7) * 128;
    const int ar = lane & 15, ak = (lane >> 4) * 8;

    f32x4 acc[4][4];
    #pragma unroll
    for (int i = 0; i < 4; ++i)
        #pragma unroll
        for (int j = 0; j < 4; ++j)
            acc[i][j] = (f32x4){0.f, 0.f, 0.f, 0.f};

    const int xr = tid >> 3, xc = (tid & 7) * 4;
    const int wkb = tid >> 5, wn4 = (tid & 31) * 4;

    for (int k0 = 0; k0 < 1024; k0 += 32) {
        __syncthreads();
        #pragma unroll
        for (int it = 0; it < 4; ++it) {
            const int r = xr + it * 32;
            const float4 v = *(const float4*)&x[(size_t)(m0 + r) * 1024 + k0 + xc];
            bf16x4 h, l; cvt4(v, h, l);
            *(bf16x4*)&Ah[r][xc] = h;
            *(bf16x4*)&Al[r][xc] = l;
        }
        {
            const size_t wb = (size_t)(k0 + wkb * 4) * 1024 + n0 + wn4;
            const float4 v0 = *(const float4*)&W[wb];
            const float4 v1 = *(const float4*)&W[wb + 1024];
            const float4 v2 = *(const float4*)&W[wb + 2048];
            const float4 v3 = *(const float4*)&W[wb + 3072];
            const float rv[4][4] = {{v0.x, v0.y, v0.z, v0.w},
                                    {v1.x, v1.y, v1.z, v1.w},
                                    {v2.x, v2.y, v2.z, v2.w},
                                    {v3.x, v3.y, v3.z, v3.w}};
            #pragma unroll
            for (int j = 0; j < 4; ++j) {
                bf16x4 h, l;
                #pragma unroll
                for (int kk = 0; kk < 4; ++kk) {
                    const float f = rv[kk][j];
                    const __bf16 hb = (__bf16)f;
                    h[kk] = hb;
                    l[kk] = (__bf16)(f - (float)hb);
                }
                *(bf16x4*)&Bh[wn4 + j][wkb * 4] = h;
                *(bf16x4*)&Bl[wn4 + j][wkb * 4] = l;
            }
        }
        __syncthreads();

        bf16x8 a_h[4], a_l[4], b_h[4], b_l[4];
        #pragma unroll
        for (int f = 0; f < 4; ++f) {
            a_h[f] = *(const bf16x8*)&Ah[wm + f * 16 + ar][ak];
            a_l[f] = *(const bf16x8*)&Al[wm + f * 16 + ar][ak];
            b_h[f] = *(const bf16x8*)&Bh[wn + f * 16 + ar][ak];
            b_l[f] = *(const bf16x8*)&Bl[wn + f * 16 + ar][ak];
        }
        #pragma unroll
        for (int i = 0; i < 4; ++i)
            #pragma unroll
            for (int j = 0; j < 4; ++j) {
                acc[i][j] = MFMA_BF16(a_h[i], b_h[j], acc[i][j]);
                acc[i][j] = MFMA_BF16(a_l[i], b_h[j], acc[i][j]);
                acc[i][j] = MFMA_BF16(a_h[i], b_l[j], acc[i][j]);
            }
    }

    const int q4 = (lane >> 4) * 4;
    #pragma unroll
    for (int j = 0; j < 4; ++j) {
        const int n = n0 + wn + j * 16 + ar;
        const float bv = bias[n];
        #pragma unroll
        for (int i = 0; i < 4; ++i) {
            const size_t base = (size_t)(m0 + wm + i * 16 + q4) * 1024 + n;
            #pragma unroll
            for (int r = 0; r < 4; ++r)
                proj[base + (size_t)r * 1024] = acc[i][j][r] + bv;
        }
    }
}

__global__ __launch_bounds__(256, 1)
void attn_kernel_fb(const float* __restrict__ y, float* __restrict__ out)
{
    __shared__ __bf16 Ph[64][40];
    __shared__ __bf16 Pl[64][40];
    __shared__ __bf16 Yh[128][40];
    __shared__ __bf16 Yl[128][40];
    __shared__ __bf16 Pbuf[64][520];

    const int tid = threadIdx.x, lane = tid & 63, wave = tid >> 6;
    const int b = blockIdx.x >> 3, sx0 = (blockIdx.x & 7) * 64;
    const size_t ybase = (size_t)b * 512 * 1024;
    const size_t pbase = ((size_t)b * 512 + sx0) * 1024;
    const int ar = lane & 15, ak = (lane >> 4) * 8, q = lane >> 4;

    f32x4 s[4][8];
    #pragma unroll
    for (int nb = 0; nb < 4; ++nb)
        #pragma unroll
        for (int f = 0; f < 8; ++f)
            s[nb][f] = (f32x4){0.f, 0.f, 0.f, 0.f};

    const int pr = tid >> 3, pc = (tid & 7) * 4;

    for (int k0 = 0; k0 < 1024; k0 += 32) {
        __syncthreads();
        #pragma unroll
        for (int it = 0; it < 2; ++it) {
            const int r = pr + it * 32;
            const float4 v = *(const float4*)&out[pbase + (size_t)r * 1024 + k0 + pc];
            bf16x4 h, l; cvt4(v, h, l);
            *(bf16x4*)&Ph[r][pc] = h;
            *(bf16x4*)&Pl[r][pc] = l;
        }
        #pragma unroll
        for (int nb = 0; nb < 4; ++nb) {
            if (nb) __syncthreads();
            const int sy0 = nb * 128;
            #pragma unroll
            for (int it = 0; it < 4; ++it) {
                const int r = pr + it * 32;
                const float4 v = *(const float4*)&y[ybase + (size_t)(sy0 + r) * 1024 + k0 + pc];
                bf16x4 h, l; cvt4(v, h, l);
                *(bf16x4*)&Yh[r][pc] = h;
                *(bf16x4*)&Yl[r][pc] = l;
            }
            __syncthreads();
            const bf16x8 a_h = *(const bf16x8*)&Ph[wave * 16 + ar][ak];
            const bf16x8 a_l = *(const bf16x8*)&Pl[wave * 16 + ar][ak];
            #pragma unroll
            for (int f = 0; f < 8; ++f) {
                const bf16x8 b_h = *(const bf16x8*)&Yh[f * 16 + ar][ak];
                const bf16x8 b_l = *(const bf16x8*)&Yl[f * 16 + ar][ak];
                s[nb][f] = MFMA_BF16(a_h, b_h, s[nb][f]);
                s[nb][f] = MFMA_BF16(a_l, b_h, s[nb][f]);
                s[nb][f] = MFMA_BF16(a_h, b_l, s[nb][f]);
            }
        }
    }

    #pragma unroll
    for (int r = 0; r < 4; ++r) {
        float m = -3.0e38f;
        #pragma unroll
        for (int nb = 0; nb < 4; ++nb)
            #pragma unroll
            for (int f = 0; f < 8; ++f)
                m = fmaxf(m, s[nb][f][r]);
        #pragma unroll
        for (int off = 1; off < 16; off <<= 1)
            m = fmaxf(m, __shfl_xor(m, off, 64));
        float sum = 0.f;
        #pragma unroll
        for (int nb = 0; nb < 4; ++nb)
            #pragma unroll
            for (int f = 0; f < 8; ++f) {
                const float e = __expf(s[nb][f][r] - m);
                s[nb][f][r] = e;
                sum += e;
            }
        #pragma unroll
        for (int off = 1; off < 16; off <<= 1)
            sum += __shfl_xor(sum, off, 64);
        const float inv = 1.0f / sum;
        #pragma unroll
        for (int nb = 0; nb < 4; ++nb)
            #pragma unroll
            for (int f = 0; f < 8; ++f)
                s[nb][f][r] *= inv;
    }
    #pragma unroll
    for (int nb = 0; nb < 4; ++nb)
        #pragma unroll
        for (int f = 0; f < 8; ++f)
            #pragma unroll
            for (int r = 0; r < 4; ++r)
                Pbuf[wave * 16 + q * 4 + r][nb * 128 + f * 16 + ar] = (__bf16)s[nb][f][r];

    const int y2kb = tid >> 5, y2n4 = (tid & 31) * 4;
    for (int d0 = 0; d0 < 1024; d0 += 128) {
        f32x4 o[8];
        #pragma unroll
        for (int f = 0; f < 8; ++f) o[f] = (f32x4){0.f, 0.f, 0.f, 0.f};

        for (int k0 = 0; k0 < 512; k0 += 32) {
            __syncthreads();
            const size_t yb = ybase + (size_t)(k0 + y2kb * 4) * 1024 + d0 + y2n4;
            const float4 v0 = *(const float4*)&y[yb];
            const float4 v1 = *(const float4*)&y[yb + 1024];
            const float4 v2 = *(const float4*)&y[yb + 2048];
            const float4 v3 = *(const float4*)&y[yb + 3072];
            const float rv[4][4] = {{v0.x, v0.y, v0.z, v0.w},
                                    {v1.x, v1.y, v1.z, v1.w},
                                    {v2.x, v2.y, v2.z, v2.w},
                                    {v3.x, v3.y, v3.z, v3.w}};
            #pragma unroll
            for (int j = 0; j < 4; ++j) {
                const bf16x4 h = (bf16x4){(__bf16)rv[0][j], (__bf16)rv[1][j],
                                          (__bf16)rv[2][j], (__bf16)rv[3][j]};
                *(bf16x4*)&Yh[y2n4 + j][y2kb * 4] = h;
            }
            __syncthreads();
            const bf16x8 a = *(const bf16x8*)&Pbuf[wave * 16 + ar][k0 + ak];
            #pragma unroll
            for (int f = 0; f < 8; ++f) {
                const bf16x8 bb = *(const bf16x8*)&Yh[f * 16 + ar][ak];
                o[f] = MFMA_BF16(a, bb, o[f]);
            }
        }
        #pragma unroll
        for (int f = 0; f < 8; ++f)
            #pragma unroll
            for (int r = 0; r < 4; ++r)
                out[pbase + (size_t)(wave * 16 + q * 4 + r) * 1024 + d0 + f * 16 + ar] = o[f][r];
    }
}

// ============================== launch ======================================

extern "C" void kernel_launch(void* const* d_in, const int* in_sizes, int n_in,
                              void* d_out, int out_size, void* d_ws, size_t ws_size,
                              hipStream_t stream) {
    (void)in_sizes; (void)n_in; (void)out_size;
    const float* x    = (const float*)d_in[0];
    const float* y    = (const float*)d_in[1];
    const float* W    = (const float*)d_in[2];
    const float* bias = (const float*)d_in[3];

    if (ws_size >= 268435456ULL) {
        _Float16* yf = (_Float16*)d_ws;
        _Float16* yT = yf + 33554432;
        _Float16* xh = yT + 33554432;
        _Float16* xl = xh + 33554432;
        _Float16* WT = xl + 33554432;
        const bool pre = ws_size >= 268435456ULL + 2097152ULL;

        if (pre) {
            prep_all_kernel<true><<<dim3(10496), dim3(256), 0, stream>>>(
                y, yf, yT, x, (f16x4*)xh, (f16x4*)xl, W, WT);
            proj_f16_kernel<true><<<dim3(2048), dim3(256), 0, stream>>>(xh, xl, WT, W, bias,
                                                                        (char*)d_out);
        } else {
            prep_all_kernel<false><<<dim3(10240), dim3(256), 0, stream>>>(
                y, yf, yT, x, (f16x4*)xh, (f16x4*)xl, W, nullptr);
            proj_f16_kernel<false><<<dim3(2048), dim3(256), 0, stream>>>(xh, xl, nullptr, W,
                                                                         bias, (char*)d_out);
        }
        attn_f16_kernel<<<dim3(512), dim3(256), 0, stream>>>(yf, yT, (char*)d_out);
    } else {
        float* out = (float*)d_out;
        proj_kernel_fb<<<dim3(256 * 8), dim3(256), 0, stream>>>(x, W, bias, out);
        attn_kernel_fb<<<dim3(64 * 8), dim3(256), 0, stream>>>(y, out);
    }
}